// Round 14
// baseline (645.546 us; speedup 1.0000x reference)
//
#include <hip/hip_runtime.h>
#include <math.h>

#define D_IN 128
#define HDIM 256

typedef __attribute__((ext_vector_type(8))) short bf16x8;
typedef __attribute__((ext_vector_type(4))) float f32x4;

// ---------------- bf16 helpers (RNE) ----------------
__device__ inline ushort f2bf(float v) {
    union { float f; unsigned u; } c; c.f = v;
    unsigned u = c.u;
    return (ushort)((u + 0x7FFFu + ((u >> 16) & 1u)) >> 16);
}
__device__ inline float bf2f(ushort h) {
    union { unsigned u; float f; } c; c.u = ((unsigned)h) << 16; return c.f;
}

// ---------------------------------------------------------------------------
__global__ __launch_bounds__(256) void zero_int_kernel(int* __restrict__ p, int n) {
    int i = blockIdx.x * 256 + threadIdx.x;
    int stride = gridDim.x * 256;
    for (; i < n; i += stride) p[i] = 0;
}

// ---------------------------------------------------------------------------
// CSR build: histogram -> 3-phase scan -> fill
// ---------------------------------------------------------------------------
__global__ __launch_bounds__(256) void hist_kernel(
    const int* __restrict__ ei, int* __restrict__ deg, int E)
{
    int e = blockIdx.x * 256 + threadIdx.x;
    if (e < E) atomicAdd(&deg[ei[E + e]], 1);
}

__global__ __launch_bounds__(256) void scan_local_kernel(
    const int* __restrict__ deg, int* __restrict__ rowptr,
    int* __restrict__ bsum, int N)
{
    __shared__ int sh[256];
    const int t = threadIdx.x;
    const int i = blockIdx.x * 256 + t;
    int v = (i < N) ? deg[i] : 0;
    sh[t] = v;
    __syncthreads();
#pragma unroll
    for (int off = 1; off < 256; off <<= 1) {
        int x = (t >= off) ? sh[t - off] : 0;
        __syncthreads();
        sh[t] += x;
        __syncthreads();
    }
    if (i < N) rowptr[i] = sh[t] - v;
    if (t == 255) bsum[blockIdx.x] = sh[255];
}

__global__ __launch_bounds__(256) void scan_bsum_kernel(
    int* __restrict__ bsum, int* __restrict__ rowptr, int nb, int N)
{
    __shared__ int sh[256];
    const int t = threadIdx.x;
    int v = (t < nb) ? bsum[t] : 0;
    sh[t] = v;
    __syncthreads();
#pragma unroll
    for (int off = 1; off < 256; off <<= 1) {
        int x = (t >= off) ? sh[t - off] : 0;
        __syncthreads();
        sh[t] += x;
        __syncthreads();
    }
    if (t < nb) bsum[t] = sh[t] - v;
    if (t == 255) rowptr[N] = sh[255];
}

__global__ __launch_bounds__(256) void scan_apply_kernel(
    int* __restrict__ rowptr, int* __restrict__ cursor,
    const int* __restrict__ bsum, int N)
{
    int i = blockIdx.x * 256 + threadIdx.x;
    if (i < N) {
        int v = rowptr[i] + bsum[blockIdx.x];
        rowptr[i] = v;
        cursor[i] = v;
    }
}

__global__ __launch_bounds__(256) void fill_kernel(
    const int* __restrict__ ei, int* __restrict__ cursor,
    int* __restrict__ srclist, int E)
{
    int e = blockIdx.x * 256 + threadIdx.x;
    if (e < E) {
        int s = ei[e];
        int d = ei[E + e];
        int pos = atomicAdd(&cursor[d], 1);
        srclist[pos] = s;
    }
}

// ---------------------------------------------------------------------------
// weight split + transpose:  W[K][256] fp32  ->  Wt_hi/Wt_lo [256][K] bf16
// ---------------------------------------------------------------------------
template<int K>
__global__ __launch_bounds__(256) void wsplit_kernel(
    const float* __restrict__ W, ushort* __restrict__ Wthi, ushort* __restrict__ Wtlo)
{
    int idx = blockIdx.x * 256 + threadIdx.x;
    if (idx >= K * 256) return;
    int k = idx >> 8;
    int c = idx & 255;
    float v = W[idx];
    ushort h = f2bf(v);
    Wthi[c * K + k] = h;
    Wtlo[c * K + k] = f2bf(v - bf2f(h));
}

// ---------------------------------------------------------------------------
// gather1: z1[v] = x[v] + sum x[u]   (fp32 in, split-bf16 out)  D=128
// TWO nodes per wave: 32 lanes x float4 each; neighbor loop unrolled x4
// ---------------------------------------------------------------------------
__global__ __launch_bounds__(256) void gather1_kernel(
    const float* __restrict__ feat, const int* __restrict__ rowptr,
    const int* __restrict__ srclist, ushort* __restrict__ Zhi,
    ushort* __restrict__ Zlo, int N)
{
    const int wid  = (blockIdx.x * 256 + threadIdx.x) >> 6;
    const int lane = threadIdx.x & 63;
    const int node = wid * 2 + (lane >> 5);
    if (node >= N) return;
    const int lo_ = rowptr[node], hi_ = rowptr[node + 1];
    const int c = (lane & 31) * 4;
    float4 a = *(const float4*)(feat + (size_t)node * D_IN + c);
    float s0 = a.x, s1 = a.y, s2 = a.z, s3 = a.w;
    int i = lo_;
    for (; i + 4 <= hi_; i += 4) {
        int n0 = srclist[i], n1 = srclist[i + 1], n2 = srclist[i + 2], n3 = srclist[i + 3];
        float4 v0 = *(const float4*)(feat + (size_t)n0 * D_IN + c);
        float4 v1 = *(const float4*)(feat + (size_t)n1 * D_IN + c);
        float4 v2 = *(const float4*)(feat + (size_t)n2 * D_IN + c);
        float4 v3 = *(const float4*)(feat + (size_t)n3 * D_IN + c);
        s0 += (v0.x + v1.x) + (v2.x + v3.x);
        s1 += (v0.y + v1.y) + (v2.y + v3.y);
        s2 += (v0.z + v1.z) + (v2.z + v3.z);
        s3 += (v0.w + v1.w) + (v2.w + v3.w);
    }
    for (; i < hi_; ++i) {
        int s = srclist[i];
        float4 v = *(const float4*)(feat + (size_t)s * D_IN + c);
        s0 += v.x; s1 += v.y; s2 += v.z; s3 += v.w;
    }
    ushort h0 = f2bf(s0), h1 = f2bf(s1), h2 = f2bf(s2), h3 = f2bf(s3);
    ushort l0 = f2bf(s0 - bf2f(h0)), l1 = f2bf(s1 - bf2f(h1));
    ushort l2 = f2bf(s2 - bf2f(h2)), l3 = f2bf(s3 - bf2f(h3));
    size_t o = (size_t)node * D_IN + c;
    uint2 oh, ol;
    oh.x = (unsigned)h0 | ((unsigned)h1 << 16); oh.y = (unsigned)h2 | ((unsigned)h3 << 16);
    ol.x = (unsigned)l0 | ((unsigned)l1 << 16); ol.y = (unsigned)l2 | ((unsigned)l3 << 16);
    *(uint2*)(Zhi + o) = oh;
    *(uint2*)(Zlo + o) = ol;
}

// ---------------------------------------------------------------------------
// gather2: z2[v] = h1[v] + sum h1[u]  (fp32 in, split-bf16 out)  D=256
// one wave per node, float4/lane, neighbor loop unrolled x4
// ---------------------------------------------------------------------------
__global__ __launch_bounds__(256) void gather2_kernel(
    const float* __restrict__ F, const int* __restrict__ rowptr,
    const int* __restrict__ srclist,
    ushort* __restrict__ Zhi, ushort* __restrict__ Zlo, int N)
{
    const int node = (blockIdx.x * 256 + threadIdx.x) >> 6;
    const int lane = threadIdx.x & 63;
    if (node >= N) return;
    const int lo_ = rowptr[node], hi_ = rowptr[node + 1];
    const int c = lane * 4;
    float4 a = *(const float4*)(F + (size_t)node * HDIM + c);
    float s0 = a.x, s1 = a.y, s2 = a.z, s3 = a.w;
    int i = lo_;
    for (; i + 4 <= hi_; i += 4) {
        int n0 = srclist[i], n1 = srclist[i + 1], n2 = srclist[i + 2], n3 = srclist[i + 3];
        float4 v0 = *(const float4*)(F + (size_t)n0 * HDIM + c);
        float4 v1 = *(const float4*)(F + (size_t)n1 * HDIM + c);
        float4 v2 = *(const float4*)(F + (size_t)n2 * HDIM + c);
        float4 v3 = *(const float4*)(F + (size_t)n3 * HDIM + c);
        s0 += (v0.x + v1.x) + (v2.x + v3.x);
        s1 += (v0.y + v1.y) + (v2.y + v3.y);
        s2 += (v0.z + v1.z) + (v2.z + v3.z);
        s3 += (v0.w + v1.w) + (v2.w + v3.w);
    }
    for (; i < hi_; ++i) {
        int s = srclist[i];
        float4 v = *(const float4*)(F + (size_t)s * HDIM + c);
        s0 += v.x; s1 += v.y; s2 += v.z; s3 += v.w;
    }
    ushort h0 = f2bf(s0), h1 = f2bf(s1), h2 = f2bf(s2), h3 = f2bf(s3);
    ushort l0 = f2bf(s0 - bf2f(h0)), l1 = f2bf(s1 - bf2f(h1));
    ushort l2 = f2bf(s2 - bf2f(h2)), l3 = f2bf(s3 - bf2f(h3));
    size_t o = (size_t)node * HDIM + c;
    uint2 oh, ol;
    oh.x = (unsigned)h0 | ((unsigned)h1 << 16); oh.y = (unsigned)h2 | ((unsigned)h3 << 16);
    ol.x = (unsigned)l0 | ((unsigned)l1 << 16); ol.y = (unsigned)l2 | ((unsigned)l3 << 16);
    *(uint2*)(Zhi + o) = oh;
    *(uint2*)(Zlo + o) = ol;
}

// ---------------------------------------------------------------------------
// split-bf16 MFMA GEMM, LDS-FREE: A and B fragments read directly from
// global (L2-resident: W hi+lo = 256KB broadcast; A rows re-read 4x, L2-hot).
// No barriers, no staging -> compiler pipelines 16 loads vs 48 MFMA per
// K-step freely. Fragment chunk l4 of each 32-k step, symmetric A/B.
// BM=64 x BN=256, 4 waves (wave wv owns cols wv*64..+63).
// OMODE: 0 = fp32 out, 1 = split-bf16 out, 2 = fused pooling (atomics)
// ---------------------------------------------------------------------------
template<int K, int OMODE>
__global__ __launch_bounds__(256) void mfma_gemm_kernel(
    const ushort* __restrict__ Ahi, const ushort* __restrict__ Alo,
    const ushort* __restrict__ Bthi, const ushort* __restrict__ Btlo,
    const float* __restrict__ Bias, float* __restrict__ OUTf,
    ushort* __restrict__ OUThi, ushort* __restrict__ OUTlo,
    const int* __restrict__ batch, float* __restrict__ psum,
    unsigned* __restrict__ pmax, int Nrows)
{
    const int t    = threadIdx.x;
    const int wv   = t >> 6;
    const int lane = t & 63;
    const int l15  = lane & 15;
    const int l4   = lane >> 4;
    const int row0 = blockIdx.x * 64;
    const int wc0  = wv * 64;

    f32x4 acc[4][4];
#pragma unroll
    for (int m = 0; m < 4; ++m)
#pragma unroll
        for (int n = 0; n < 4; ++n) acc[m][n] = (f32x4){0.f, 0.f, 0.f, 0.f};

    // per-lane fragment base addresses (chunk l4 of each 32-k step)
    size_t abase[4], bbase[4];
#pragma unroll
    for (int m = 0; m < 4; ++m) {
        int arow = min(row0 + m * 16 + l15, Nrows - 1);
        abase[m] = (size_t)arow * K + l4 * 8;
    }
#pragma unroll
    for (int n = 0; n < 4; ++n) {
        int bcol = wc0 + n * 16 + l15;
        bbase[n] = (size_t)bcol * K + l4 * 8;
    }

    for (int k0 = 0; k0 < K; k0 += 32) {
        bf16x8 ah[4], al[4], bh[4], bl[4];
#pragma unroll
        for (int m = 0; m < 4; ++m) {
            ah[m] = *(const bf16x8*)(Ahi + abase[m] + k0);
            al[m] = *(const bf16x8*)(Alo + abase[m] + k0);
        }
#pragma unroll
        for (int n = 0; n < 4; ++n) {
            bh[n] = *(const bf16x8*)(Bthi + bbase[n] + k0);
            bl[n] = *(const bf16x8*)(Btlo + bbase[n] + k0);
        }
#pragma unroll
        for (int m = 0; m < 4; ++m)
#pragma unroll
            for (int n = 0; n < 4; ++n) {
                acc[m][n] = __builtin_amdgcn_mfma_f32_16x16x32_bf16(ah[m], bh[n], acc[m][n], 0, 0, 0);
                acc[m][n] = __builtin_amdgcn_mfma_f32_16x16x32_bf16(ah[m], bl[n], acc[m][n], 0, 0, 0);
                acc[m][n] = __builtin_amdgcn_mfma_f32_16x16x32_bf16(al[m], bh[n], acc[m][n], 0, 0, 0);
            }
    }

    // epilogue: C/D layout col=lane&15, row=(lane>>4)*4+reg (HW-verified)
#pragma unroll
    for (int n = 0; n < 4; ++n) {
        const int ocol = wc0 + n * 16 + l15;
        const float bs = Bias[ocol];
        if (OMODE == 2) {
            // fused mean/max pooling: rows are batch-sorted; per-lane
            // flush-on-graph-change local segments, then atomics.
            int gcur = -1; float ssum = 0.f; float smax = 0.f;
#pragma unroll
            for (int m = 0; m < 4; ++m) {
#pragma unroll
                for (int r = 0; r < 4; ++r) {
                    int orow = row0 + m * 16 + l4 * 4 + r;   // increasing in m,r
                    if (orow < Nrows) {
                        float v = fmaxf(acc[m][n][r] + bs, 0.f);
                        int g = batch[orow];
                        if (g != gcur) {
                            if (gcur >= 0) {
                                atomicAdd(&psum[gcur * HDIM + ocol], ssum);
                                atomicMax(&pmax[gcur * HDIM + ocol], __float_as_uint(smax));
                            }
                            gcur = g; ssum = 0.f; smax = 0.f;
                        }
                        ssum += v; smax = fmaxf(smax, v);
                    }
                }
            }
            if (gcur >= 0) {
                atomicAdd(&psum[gcur * HDIM + ocol], ssum);
                atomicMax(&pmax[gcur * HDIM + ocol], __float_as_uint(smax));
            }
        } else {
#pragma unroll
            for (int m = 0; m < 4; ++m) {
#pragma unroll
                for (int r = 0; r < 4; ++r) {
                    int orow = row0 + m * 16 + l4 * 4 + r;
                    if (orow < Nrows) {
                        float v = fmaxf(acc[m][n][r] + bs, 0.f);
                        size_t o = (size_t)orow * HDIM + ocol;
                        if (OMODE == 1) {
                            ushort h = f2bf(v);
                            OUThi[o] = h;
                            OUTlo[o] = f2bf(v - bf2f(h));
                        } else {
                            OUTf[o] = v;
                        }
                    }
                }
            }
        }
    }
}

// ---------------------------------------------------------------------------
// pool_final: one block per graph; psum/pmax already aggregated by gemm4
// ---------------------------------------------------------------------------
__global__ __launch_bounds__(256) void pool_final_kernel(
    const float* __restrict__ psum, const unsigned* __restrict__ pmax,
    const int* __restrict__ batch,
    const float* __restrict__ Wf1, const float* __restrict__ bf1,
    const float* __restrict__ Wf2, const float* __restrict__ bf2,
    float* __restrict__ out, int N)
{
    const int g = blockIdx.x;
    const int t = threadIdx.x;

    __shared__ int s_bounds[2];
    if (t < 2) {
        int target = g + t;
        int lo = 0, hi = N;
        while (lo < hi) {
            int mid = (lo + hi) >> 1;
            if (batch[mid] < target) lo = mid + 1; else hi = mid;
        }
        s_bounds[t] = lo;
    }
    __syncthreads();
    const int cnt = s_bounds[1] - s_bounds[0];

    float sum = psum[g * HDIM + t];
    float mx  = __uint_as_float(pmax[g * HDIM + t]);   // 0 for empty graphs (init)

    __shared__ float p[2 * HDIM];
    p[t]        = sum / (float)(cnt > 1 ? cnt : 1);
    p[HDIM + t] = mx;
    __syncthreads();

    float acc = bf1[t];
#pragma unroll 8
    for (int k = 0; k < 2 * HDIM; ++k)
        acc += p[k] * Wf1[k * HDIM + t];
    float hval = fmaxf(acc, 0.f);

    float partial = hval * Wf2[t];
#pragma unroll
    for (int off = 32; off > 0; off >>= 1)
        partial += __shfl_down(partial, off);
    __shared__ float red[4];
    if ((t & 63) == 0) red[t >> 6] = partial;
    __syncthreads();
    if (t == 0) out[g] = red[0] + red[1] + red[2] + red[3] + bf2[0];
}

// ---------------------------------------------------------------------------
extern "C" void kernel_launch(void* const* d_in, const int* in_sizes, int n_in,
                              void* d_out, int out_size, void* d_ws, size_t ws_size,
                              hipStream_t stream)
{
    const float* x     = (const float*)d_in[0];
    const int*   ei    = (const int*)d_in[1];
    const int*   batch = (const int*)d_in[2];
    const float* W1 = (const float*)d_in[3];
    const float* b1 = (const float*)d_in[4];
    const float* W2 = (const float*)d_in[5];
    const float* b2 = (const float*)d_in[6];
    const float* W3 = (const float*)d_in[7];
    const float* b3 = (const float*)d_in[8];
    const float* W4 = (const float*)d_in[9];
    const float* b4 = (const float*)d_in[10];
    const float* Wf1 = (const float*)d_in[11];
    const float* bf1 = (const float*)d_in[12];
    const float* Wf2 = (const float*)d_in[13];
    const float* bf2 = (const float*)d_in[14];
    float* out = (float*)d_out;

    const int N  = in_sizes[0] / D_IN;   // 50000
    const int E  = in_sizes[1] / 2;      // 600000
    const int Gn = out_size;             // 128

    // ---- workspace layout ----
    const size_t R = (size_t)N * HDIM;   // floats per region
    float* R0f = (float*)d_ws;
    float* R1f = R0f + R;
    ushort* R0u = (ushort*)R0f;
    ushort* R1u = (ushort*)R1f;

    ushort* wbuf = (ushort*)(R1f + R);
    ushort* W1thi = wbuf;
    ushort* W1tlo = W1thi + 128 * 256;
    ushort* W2thi = W1tlo + 128 * 256;
    ushort* W2tlo = W2thi + 256 * 256;
    ushort* W3thi = W2tlo + 256 * 256;
    ushort* W3tlo = W3thi + 256 * 256;
    ushort* W4thi = W3tlo + 256 * 256;
    ushort* W4tlo = W4thi + 256 * 256;

    int* rowptr  = (int*)(W4tlo + 256 * 256);
    int* cursor  = rowptr + (N + 1);
    int* srclist = cursor + N;
    float* psum     = (float*)(srclist + E);
    unsigned* pmax  = (unsigned*)(psum + (size_t)Gn * HDIM);
    int* bsum       = (int*)(pmax + (size_t)Gn * HDIM);

    const int gblocks  = (N + 63) / 64;
    const int eblocks  = (E + 255) / 256;
    const int wblocks2 = (N + 3) / 4;           // gather2: 1 node/wave
    const int wblocks1 = ((N + 1) / 2 + 3) / 4; // gather1: 2 nodes/wave
    const int nb       = (N + 255) / 256;

    // ---- CSR build (multi-block scan) ----
    zero_int_kernel<<<64, 256, 0, stream>>>(cursor, N);
    hist_kernel<<<eblocks, 256, 0, stream>>>(ei, cursor, E);
    scan_local_kernel<<<nb, 256, 0, stream>>>(cursor, rowptr, bsum, N);
    scan_bsum_kernel<<<1, 256, 0, stream>>>(bsum, rowptr, nb, N);
    scan_apply_kernel<<<nb, 256, 0, stream>>>(rowptr, cursor, bsum, N);
    fill_kernel<<<eblocks, 256, 0, stream>>>(ei, cursor, srclist, E);

    // ---- weight split+transpose; zero pooling accumulators ----
    wsplit_kernel<128><<<128, 256, 0, stream>>>(W1, W1thi, W1tlo);
    wsplit_kernel<256><<<256, 256, 0, stream>>>(W2, W2thi, W2tlo);
    wsplit_kernel<256><<<256, 256, 0, stream>>>(W3, W3thi, W3tlo);
    wsplit_kernel<256><<<256, 256, 0, stream>>>(W4, W4thi, W4tlo);
    zero_int_kernel<<<64, 256, 0, stream>>>((int*)psum, 2 * Gn * HDIM);  // psum+pmax

    // buffer views
    ushort* Z1hi = R0u;                 ushort* Z1lo = R0u + (size_t)N * D_IN;  // [N][128] split
    ushort* T1hi = R1u;                 ushort* T1lo = R1u + R;                 // [N][256] split
    float*  H1   = R0f;                                                         // [N][256] fp32
    ushort* Z2hi = R1u;                 ushort* Z2lo = R1u + R;                 // [N][256] split
    ushort* T2hi = R0u;                 ushort* T2lo = R0u + R;                 // [N][256] split

    // ---- conv1 ----
    gather1_kernel<<<wblocks1, 256, 0, stream>>>(x, rowptr, srclist, Z1hi, Z1lo, N);
    mfma_gemm_kernel<128, 1><<<gblocks, 256, 0, stream>>>(
        Z1hi, Z1lo, W1thi, W1tlo, b1, nullptr, T1hi, T1lo, nullptr, nullptr, nullptr, N);
    mfma_gemm_kernel<256, 0><<<gblocks, 256, 0, stream>>>(
        T1hi, T1lo, W2thi, W2tlo, b2, H1, nullptr, nullptr, nullptr, nullptr, nullptr, N);

    // ---- conv2 ----
    gather2_kernel<<<wblocks2, 256, 0, stream>>>(H1, rowptr, srclist, Z2hi, Z2lo, N);
    mfma_gemm_kernel<256, 1><<<gblocks, 256, 0, stream>>>(
        Z2hi, Z2lo, W3thi, W3tlo, b3, nullptr, T2hi, T2lo, nullptr, nullptr, nullptr, N);
    // gemm4 with fused mean/max pooling (no H2 materialization)
    mfma_gemm_kernel<256, 2><<<gblocks, 256, 0, stream>>>(
        T2hi, T2lo, W4thi, W4tlo, b4, nullptr, nullptr, nullptr, batch, psum, pmax, N);

    // ---- final MLP ----
    pool_final_kernel<<<Gn, 256, 0, stream>>>(psum, pmax, batch,
                                              Wf1, bf1, Wf2, bf2, out, N);
}

// Round 15
// 526.569 us; speedup vs baseline: 1.2259x; 1.2259x over previous
//
#include <hip/hip_runtime.h>
#include <math.h>

#define D_IN 128
#define HDIM 256

typedef __attribute__((ext_vector_type(8))) short bf16x8;
typedef __attribute__((ext_vector_type(4))) float f32x4;

#define GLOBAL_AS __attribute__((address_space(1)))
#define LDS_AS    __attribute__((address_space(3)))

// async 16B/lane global->LDS (dest = wave-uniform base + lane*16)
__device__ __forceinline__ void gload16(const void* g, void* l) {
    __builtin_amdgcn_global_load_lds((const GLOBAL_AS void*)g, (LDS_AS void*)l, 16, 0, 0);
}

// ---------------- bf16 helpers (RNE) ----------------
__device__ inline ushort f2bf(float v) {
    union { float f; unsigned u; } c; c.f = v;
    unsigned u = c.u;
    return (ushort)((u + 0x7FFFu + ((u >> 16) & 1u)) >> 16);
}
__device__ inline float bf2f(ushort h) {
    union { unsigned u; float f; } c; c.u = ((unsigned)h) << 16; return c.f;
}

// ---------------------------------------------------------------------------
__global__ __launch_bounds__(256) void zero_int_kernel(int* __restrict__ p, int n) {
    int i = blockIdx.x * 256 + threadIdx.x;
    int stride = gridDim.x * 256;
    for (; i < n; i += stride) p[i] = 0;
}

// ---------------------------------------------------------------------------
// CSR build: histogram -> 3-phase scan -> fill
// ---------------------------------------------------------------------------
__global__ __launch_bounds__(256) void hist_kernel(
    const int* __restrict__ ei, int* __restrict__ deg, int E)
{
    int e = blockIdx.x * 256 + threadIdx.x;
    if (e < E) atomicAdd(&deg[ei[E + e]], 1);
}

__global__ __launch_bounds__(256) void scan_local_kernel(
    const int* __restrict__ deg, int* __restrict__ rowptr,
    int* __restrict__ bsum, int N)
{
    __shared__ int sh[256];
    const int t = threadIdx.x;
    const int i = blockIdx.x * 256 + t;
    int v = (i < N) ? deg[i] : 0;
    sh[t] = v;
    __syncthreads();
#pragma unroll
    for (int off = 1; off < 256; off <<= 1) {
        int x = (t >= off) ? sh[t - off] : 0;
        __syncthreads();
        sh[t] += x;
        __syncthreads();
    }
    if (i < N) rowptr[i] = sh[t] - v;
    if (t == 255) bsum[blockIdx.x] = sh[255];
}

__global__ __launch_bounds__(256) void scan_bsum_kernel(
    int* __restrict__ bsum, int* __restrict__ rowptr, int nb, int N)
{
    __shared__ int sh[256];
    const int t = threadIdx.x;
    int v = (t < nb) ? bsum[t] : 0;
    sh[t] = v;
    __syncthreads();
#pragma unroll
    for (int off = 1; off < 256; off <<= 1) {
        int x = (t >= off) ? sh[t - off] : 0;
        __syncthreads();
        sh[t] += x;
        __syncthreads();
    }
    if (t < nb) bsum[t] = sh[t] - v;
    if (t == 255) rowptr[N] = sh[255];
}

__global__ __launch_bounds__(256) void scan_apply_kernel(
    int* __restrict__ rowptr, int* __restrict__ cursor,
    const int* __restrict__ bsum, int N)
{
    int i = blockIdx.x * 256 + threadIdx.x;
    if (i < N) {
        int v = rowptr[i] + bsum[blockIdx.x];
        rowptr[i] = v;
        cursor[i] = v;
    }
}

__global__ __launch_bounds__(256) void fill_kernel(
    const int* __restrict__ ei, int* __restrict__ cursor,
    int* __restrict__ srclist, int E)
{
    int e = blockIdx.x * 256 + threadIdx.x;
    if (e < E) {
        int s = ei[e];
        int d = ei[E + e];
        int pos = atomicAdd(&cursor[d], 1);
        srclist[pos] = s;
    }
}

// ---------------------------------------------------------------------------
// fused weight split + transpose for all four W matrices (one launch)
// ---------------------------------------------------------------------------
__global__ __launch_bounds__(256) void wsplit_all_kernel(
    const float* __restrict__ W1, const float* __restrict__ W2,
    const float* __restrict__ W3, const float* __restrict__ W4,
    ushort* __restrict__ W1thi, ushort* __restrict__ W1tlo,
    ushort* __restrict__ W2thi, ushort* __restrict__ W2tlo,
    ushort* __restrict__ W3thi, ushort* __restrict__ W3tlo,
    ushort* __restrict__ W4thi, ushort* __restrict__ W4tlo)
{
    int idx = blockIdx.x * 256 + threadIdx.x;
    if (idx < 128 * 256) {               // W1: K=128
        int k = idx >> 8, c = idx & 255;
        float v = W1[idx];
        ushort h = f2bf(v);
        W1thi[c * 128 + k] = h;
        W1tlo[c * 128 + k] = f2bf(v - bf2f(h));
    } else {                             // W2/W3/W4: K=256
        int r = idx - 128 * 256;
        int which = r >> 16;             // 65536 elements per matrix
        r &= 65535;
        if (which > 2) return;
        const float* W = (which == 0) ? W2 : (which == 1) ? W3 : W4;
        ushort* Whi = (which == 0) ? W2thi : (which == 1) ? W3thi : W4thi;
        ushort* Wlo = (which == 0) ? W2tlo : (which == 1) ? W3tlo : W4tlo;
        int k = r >> 8, c = r & 255;
        float v = W[r];
        ushort h = f2bf(v);
        Whi[c * 256 + k] = h;
        Wlo[c * 256 + k] = f2bf(v - bf2f(h));
    }
}

// ---------------------------------------------------------------------------
// gather1: z1[v] = x[v] + sum x[u]   (fp32 in, split-bf16 out)  D=128
// TWO nodes per wave: 32 lanes x float4 each; neighbor loop unrolled x4
// ---------------------------------------------------------------------------
__global__ __launch_bounds__(256) void gather1_kernel(
    const float* __restrict__ feat, const int* __restrict__ rowptr,
    const int* __restrict__ srclist, ushort* __restrict__ Zhi,
    ushort* __restrict__ Zlo, int N)
{
    const int wid  = (blockIdx.x * 256 + threadIdx.x) >> 6;
    const int lane = threadIdx.x & 63;
    const int node = wid * 2 + (lane >> 5);
    if (node >= N) return;
    const int lo_ = rowptr[node], hi_ = rowptr[node + 1];
    const int c = (lane & 31) * 4;
    float4 a = *(const float4*)(feat + (size_t)node * D_IN + c);
    float s0 = a.x, s1 = a.y, s2 = a.z, s3 = a.w;
    int i = lo_;
    for (; i + 4 <= hi_; i += 4) {
        int n0 = srclist[i], n1 = srclist[i + 1], n2 = srclist[i + 2], n3 = srclist[i + 3];
        float4 v0 = *(const float4*)(feat + (size_t)n0 * D_IN + c);
        float4 v1 = *(const float4*)(feat + (size_t)n1 * D_IN + c);
        float4 v2 = *(const float4*)(feat + (size_t)n2 * D_IN + c);
        float4 v3 = *(const float4*)(feat + (size_t)n3 * D_IN + c);
        s0 += (v0.x + v1.x) + (v2.x + v3.x);
        s1 += (v0.y + v1.y) + (v2.y + v3.y);
        s2 += (v0.z + v1.z) + (v2.z + v3.z);
        s3 += (v0.w + v1.w) + (v2.w + v3.w);
    }
    for (; i < hi_; ++i) {
        int s = srclist[i];
        float4 v = *(const float4*)(feat + (size_t)s * D_IN + c);
        s0 += v.x; s1 += v.y; s2 += v.z; s3 += v.w;
    }
    ushort h0 = f2bf(s0), h1 = f2bf(s1), h2 = f2bf(s2), h3 = f2bf(s3);
    ushort l0 = f2bf(s0 - bf2f(h0)), l1 = f2bf(s1 - bf2f(h1));
    ushort l2 = f2bf(s2 - bf2f(h2)), l3 = f2bf(s3 - bf2f(h3));
    size_t o = (size_t)node * D_IN + c;
    uint2 oh, ol;
    oh.x = (unsigned)h0 | ((unsigned)h1 << 16); oh.y = (unsigned)h2 | ((unsigned)h3 << 16);
    ol.x = (unsigned)l0 | ((unsigned)l1 << 16); ol.y = (unsigned)l2 | ((unsigned)l3 << 16);
    *(uint2*)(Zhi + o) = oh;
    *(uint2*)(Zlo + o) = ol;
}

// ---------------------------------------------------------------------------
// gather2: z2[v] = h1[v] + sum h1[u]  (fp32 in, split-bf16 out)  D=256
// one wave per node, float4/lane, neighbor loop unrolled x4
// ---------------------------------------------------------------------------
__global__ __launch_bounds__(256) void gather2_kernel(
    const float* __restrict__ F, const int* __restrict__ rowptr,
    const int* __restrict__ srclist,
    ushort* __restrict__ Zhi, ushort* __restrict__ Zlo, int N)
{
    const int node = (blockIdx.x * 256 + threadIdx.x) >> 6;
    const int lane = threadIdx.x & 63;
    if (node >= N) return;
    const int lo_ = rowptr[node], hi_ = rowptr[node + 1];
    const int c = lane * 4;
    float4 a = *(const float4*)(F + (size_t)node * HDIM + c);
    float s0 = a.x, s1 = a.y, s2 = a.z, s3 = a.w;
    int i = lo_;
    for (; i + 4 <= hi_; i += 4) {
        int n0 = srclist[i], n1 = srclist[i + 1], n2 = srclist[i + 2], n3 = srclist[i + 3];
        float4 v0 = *(const float4*)(F + (size_t)n0 * HDIM + c);
        float4 v1 = *(const float4*)(F + (size_t)n1 * HDIM + c);
        float4 v2 = *(const float4*)(F + (size_t)n2 * HDIM + c);
        float4 v3 = *(const float4*)(F + (size_t)n3 * HDIM + c);
        s0 += (v0.x + v1.x) + (v2.x + v3.x);
        s1 += (v0.y + v1.y) + (v2.y + v3.y);
        s2 += (v0.z + v1.z) + (v2.z + v3.z);
        s3 += (v0.w + v1.w) + (v2.w + v3.w);
    }
    for (; i < hi_; ++i) {
        int s = srclist[i];
        float4 v = *(const float4*)(F + (size_t)s * HDIM + c);
        s0 += v.x; s1 += v.y; s2 += v.z; s3 += v.w;
    }
    ushort h0 = f2bf(s0), h1 = f2bf(s1), h2 = f2bf(s2), h3 = f2bf(s3);
    ushort l0 = f2bf(s0 - bf2f(h0)), l1 = f2bf(s1 - bf2f(h1));
    ushort l2 = f2bf(s2 - bf2f(h2)), l3 = f2bf(s3 - bf2f(h3));
    size_t o = (size_t)node * HDIM + c;
    uint2 oh, ol;
    oh.x = (unsigned)h0 | ((unsigned)h1 << 16); oh.y = (unsigned)h2 | ((unsigned)h3 << 16);
    ol.x = (unsigned)l0 | ((unsigned)l1 << 16); ol.y = (unsigned)l2 | ((unsigned)l3 << 16);
    *(uint2*)(Zhi + o) = oh;
    *(uint2*)(Zlo + o) = ol;
}

// ---------------------------------------------------------------------------
// split-bf16 MFMA GEMM (r13 structure: single-buffered, BM=64 x BN=256,
// global_load_lds staging, XOR involution swizzle).
// OMODE: 0 = fp32 out, 1 = split-bf16 out, 2 = fused pooling (atomics)
// ---------------------------------------------------------------------------
template<int K, int OMODE>
__global__ __launch_bounds__(256) void mfma_gemm_kernel(
    const ushort* __restrict__ Ahi, const ushort* __restrict__ Alo,
    const ushort* __restrict__ Bthi, const ushort* __restrict__ Btlo,
    const float* __restrict__ Bias, float* __restrict__ OUTf,
    ushort* __restrict__ OUThi, ushort* __restrict__ OUTlo,
    const int* __restrict__ batch, float* __restrict__ psum,
    unsigned* __restrict__ pmax, int Nrows)
{
    __shared__ ushort As[2][64][32];    // 8 KB
    __shared__ ushort Ws[2][256][32];   // 32 KB
    const int t    = threadIdx.x;
    const int wv   = t >> 6;
    const int lane = t & 63;
    const int l15  = lane & 15;
    const int l4   = lane >> 4;
    const int row0 = blockIdx.x * 64;
    const int wc0  = wv * 64;

    const int srow   = lane >> 2;                        // staged row within 16-group
    const int schunk = (lane & 3) ^ ((lane >> 3) & 3);   // swizzled source k-chunk
    const int rchunk = (l4 ^ ((l15 >> 1) & 3)) * 8;      // ds_read k-offset (ushorts)

    f32x4 acc[4][4];
#pragma unroll
    for (int m = 0; m < 4; ++m)
#pragma unroll
        for (int n = 0; n < 4; ++n) acc[m][n] = (f32x4){0.f, 0.f, 0.f, 0.f};

    const int agrow = min(row0 + wv * 16 + srow, Nrows - 1);
    const size_t abase = (size_t)agrow * K + schunk * 8;

    for (int k0 = 0; k0 < K; k0 += 32) {
        // W^T staging: 4 row-groups x (hi,lo) per wave
#pragma unroll
        for (int j = 0; j < 4; ++j) {
            const int g = wv * 4 + j;
            const size_t wb = (size_t)(g * 16 + srow) * K + k0 + schunk * 8;
            gload16(Bthi + wb, &Ws[0][g * 16][0]);
            gload16(Btlo + wb, &Ws[1][g * 16][0]);
        }
        // A staging: 1 row-group x (hi,lo) per wave
        gload16(Ahi + abase + k0, &As[0][wv * 16][0]);
        gload16(Alo + abase + k0, &As[1][wv * 16][0]);
        __syncthreads();

        bf16x8 ah[4], al[4], bh[4], bl[4];
#pragma unroll
        for (int m = 0; m < 4; ++m) {
            ah[m] = *(const bf16x8*)&As[0][m * 16 + l15][rchunk];
            al[m] = *(const bf16x8*)&As[1][m * 16 + l15][rchunk];
        }
#pragma unroll
        for (int n = 0; n < 4; ++n) {
            bh[n] = *(const bf16x8*)&Ws[0][wc0 + n * 16 + l15][rchunk];
            bl[n] = *(const bf16x8*)&Ws[1][wc0 + n * 16 + l15][rchunk];
        }
#pragma unroll
        for (int m = 0; m < 4; ++m)
#pragma unroll
            for (int n = 0; n < 4; ++n) {
                acc[m][n] = __builtin_amdgcn_mfma_f32_16x16x32_bf16(ah[m], bh[n], acc[m][n], 0, 0, 0);
                acc[m][n] = __builtin_amdgcn_mfma_f32_16x16x32_bf16(ah[m], bl[n], acc[m][n], 0, 0, 0);
                acc[m][n] = __builtin_amdgcn_mfma_f32_16x16x32_bf16(al[m], bh[n], acc[m][n], 0, 0, 0);
            }
        __syncthreads();
    }

    // epilogue: C/D layout col=lane&15, row=(lane>>4)*4+reg (HW-verified)
#pragma unroll
    for (int n = 0; n < 4; ++n) {
        const int ocol = wc0 + n * 16 + l15;
        const float bs = Bias[ocol];
        if (OMODE == 2) {
            // fused mean/max pooling: rows are batch-sorted; per-lane
            // flush-on-graph-change local segments, then atomics.
            int gcur = -1; float ssum = 0.f; float smax = 0.f;
#pragma unroll
            for (int m = 0; m < 4; ++m) {
#pragma unroll
                for (int r = 0; r < 4; ++r) {
                    int orow = row0 + m * 16 + l4 * 4 + r;   // increasing in m,r
                    if (orow < Nrows) {
                        float v = fmaxf(acc[m][n][r] + bs, 0.f);
                        int g = batch[orow];
                        if (g != gcur) {
                            if (gcur >= 0) {
                                atomicAdd(&psum[gcur * HDIM + ocol], ssum);
                                atomicMax(&pmax[gcur * HDIM + ocol], __float_as_uint(smax));
                            }
                            gcur = g; ssum = 0.f; smax = 0.f;
                        }
                        ssum += v; smax = fmaxf(smax, v);
                    }
                }
            }
            if (gcur >= 0) {
                atomicAdd(&psum[gcur * HDIM + ocol], ssum);
                atomicMax(&pmax[gcur * HDIM + ocol], __float_as_uint(smax));
            }
        } else {
#pragma unroll
            for (int m = 0; m < 4; ++m) {
#pragma unroll
                for (int r = 0; r < 4; ++r) {
                    int orow = row0 + m * 16 + l4 * 4 + r;
                    if (orow < Nrows) {
                        float v = fmaxf(acc[m][n][r] + bs, 0.f);
                        size_t o = (size_t)orow * HDIM + ocol;
                        if (OMODE == 1) {
                            ushort h = f2bf(v);
                            OUThi[o] = h;
                            OUTlo[o] = f2bf(v - bf2f(h));
                        } else {
                            OUTf[o] = v;
                        }
                    }
                }
            }
        }
    }
}

// ---------------------------------------------------------------------------
// pool_final: one block per graph; psum/pmax already aggregated by gemm4
// ---------------------------------------------------------------------------
__global__ __launch_bounds__(256) void pool_final_kernel(
    const float* __restrict__ psum, const unsigned* __restrict__ pmax,
    const int* __restrict__ batch,
    const float* __restrict__ Wf1, const float* __restrict__ bf1,
    const float* __restrict__ Wf2, const float* __restrict__ bf2,
    float* __restrict__ out, int N)
{
    const int g = blockIdx.x;
    const int t = threadIdx.x;

    __shared__ int s_bounds[2];
    if (t < 2) {
        int target = g + t;
        int lo = 0, hi = N;
        while (lo < hi) {
            int mid = (lo + hi) >> 1;
            if (batch[mid] < target) lo = mid + 1; else hi = mid;
        }
        s_bounds[t] = lo;
    }
    __syncthreads();
    const int cnt = s_bounds[1] - s_bounds[0];

    float sum = psum[g * HDIM + t];
    float mx  = __uint_as_float(pmax[g * HDIM + t]);   // 0 for empty graphs (init)

    __shared__ float p[2 * HDIM];
    p[t]        = sum / (float)(cnt > 1 ? cnt : 1);
    p[HDIM + t] = mx;
    __syncthreads();

    float acc = bf1[t];
#pragma unroll 8
    for (int k = 0; k < 2 * HDIM; ++k)
        acc += p[k] * Wf1[k * HDIM + t];
    float hval = fmaxf(acc, 0.f);

    float partial = hval * Wf2[t];
#pragma unroll
    for (int off = 32; off > 0; off >>= 1)
        partial += __shfl_down(partial, off);
    __shared__ float red[4];
    if ((t & 63) == 0) red[t >> 6] = partial;
    __syncthreads();
    if (t == 0) out[g] = red[0] + red[1] + red[2] + red[3] + bf2[0];
}

// ---------------------------------------------------------------------------
extern "C" void kernel_launch(void* const* d_in, const int* in_sizes, int n_in,
                              void* d_out, int out_size, void* d_ws, size_t ws_size,
                              hipStream_t stream)
{
    const float* x     = (const float*)d_in[0];
    const int*   ei    = (const int*)d_in[1];
    const int*   batch = (const int*)d_in[2];
    const float* W1 = (const float*)d_in[3];
    const float* b1 = (const float*)d_in[4];
    const float* W2 = (const float*)d_in[5];
    const float* b2 = (const float*)d_in[6];
    const float* W3 = (const float*)d_in[7];
    const float* b3 = (const float*)d_in[8];
    const float* W4 = (const float*)d_in[9];
    const float* b4 = (const float*)d_in[10];
    const float* Wf1 = (const float*)d_in[11];
    const float* bf1 = (const float*)d_in[12];
    const float* Wf2 = (const float*)d_in[13];
    const float* bf2 = (const float*)d_in[14];
    float* out = (float*)d_out;

    const int N  = in_sizes[0] / D_IN;   // 50000
    const int E  = in_sizes[1] / 2;      // 600000
    const int Gn = out_size;             // 128

    // ---- workspace layout ----
    const size_t R = (size_t)N * HDIM;   // floats per region
    float* R0f = (float*)d_ws;
    float* R1f = R0f + R;
    ushort* R0u = (ushort*)R0f;
    ushort* R1u = (ushort*)R1f;

    ushort* wbuf = (ushort*)(R1f + R);
    ushort* W1thi = wbuf;
    ushort* W1tlo = W1thi + 128 * 256;
    ushort* W2thi = W1tlo + 128 * 256;
    ushort* W2tlo = W2thi + 256 * 256;
    ushort* W3thi = W2tlo + 256 * 256;
    ushort* W3tlo = W3thi + 256 * 256;
    ushort* W4thi = W3tlo + 256 * 256;
    ushort* W4tlo = W4thi + 256 * 256;

    int* rowptr  = (int*)(W4tlo + 256 * 256);
    int* cursor  = rowptr + (N + 1);
    int* srclist = cursor + N;
    float* psum     = (float*)(srclist + E);
    unsigned* pmax  = (unsigned*)(psum + (size_t)Gn * HDIM);
    int* bsum       = (int*)(pmax + (size_t)Gn * HDIM);

    const int gblocks  = (N + 63) / 64;
    const int eblocks  = (E + 255) / 256;
    const int wblocks2 = (N + 3) / 4;           // gather2: 1 node/wave
    const int wblocks1 = ((N + 1) / 2 + 3) / 4; // gather1: 2 nodes/wave
    const int nb       = (N + 255) / 256;
    const int wsb      = (128 * 256 + 3 * 256 * 256 + 255) / 256;  // wsplit grid

    // ---- CSR build (multi-block scan) ----
    zero_int_kernel<<<64, 256, 0, stream>>>(cursor, N);
    hist_kernel<<<eblocks, 256, 0, stream>>>(ei, cursor, E);
    scan_local_kernel<<<nb, 256, 0, stream>>>(cursor, rowptr, bsum, N);
    scan_bsum_kernel<<<1, 256, 0, stream>>>(bsum, rowptr, nb, N);
    scan_apply_kernel<<<nb, 256, 0, stream>>>(rowptr, cursor, bsum, N);
    fill_kernel<<<eblocks, 256, 0, stream>>>(ei, cursor, srclist, E);

    // ---- weight split+transpose (fused) + zero pooling accumulators ----
    wsplit_all_kernel<<<wsb, 256, 0, stream>>>(
        W1, W2, W3, W4, W1thi, W1tlo, W2thi, W2tlo, W3thi, W3tlo, W4thi, W4tlo);
    zero_int_kernel<<<64, 256, 0, stream>>>((int*)psum, 2 * Gn * HDIM);  // psum+pmax

    // buffer views
    ushort* Z1hi = R0u;                 ushort* Z1lo = R0u + (size_t)N * D_IN;  // [N][128] split
    ushort* T1hi = R1u;                 ushort* T1lo = R1u + R;                 // [N][256] split
    float*  H1   = R0f;                                                         // [N][256] fp32
    ushort* Z2hi = R1u;                 ushort* Z2lo = R1u + R;                 // [N][256] split
    ushort* T2hi = R0u;                 ushort* T2lo = R0u + R;                 // [N][256] split

    // ---- conv1 ----
    gather1_kernel<<<wblocks1, 256, 0, stream>>>(x, rowptr, srclist, Z1hi, Z1lo, N);
    mfma_gemm_kernel<128, 1><<<gblocks, 256, 0, stream>>>(
        Z1hi, Z1lo, W1thi, W1tlo, b1, nullptr, T1hi, T1lo, nullptr, nullptr, nullptr, N);
    mfma_gemm_kernel<256, 0><<<gblocks, 256, 0, stream>>>(
        T1hi, T1lo, W2thi, W2tlo, b2, H1, nullptr, nullptr, nullptr, nullptr, nullptr, N);

    // ---- conv2 ----
    gather2_kernel<<<wblocks2, 256, 0, stream>>>(H1, rowptr, srclist, Z2hi, Z2lo, N);
    mfma_gemm_kernel<256, 1><<<gblocks, 256, 0, stream>>>(
        Z2hi, Z2lo, W3thi, W3tlo, b3, nullptr, T2hi, T2lo, nullptr, nullptr, nullptr, N);
    // gemm4 with fused mean/max pooling (no H2 materialization)
    mfma_gemm_kernel<256, 2><<<gblocks, 256, 0, stream>>>(
        T2hi, T2lo, W4thi, W4tlo, b4, nullptr, nullptr, nullptr, batch, psum, pmax, N);

    // ---- final MLP ----
    pool_final_kernel<<<Gn, 256, 0, stream>>>(psum, pmax, batch,
                                              Wf1, bf1, Wf2, bf2, out, N);
}